// Round 1
// baseline (346.004 us; speedup 1.0000x reference)
//
#include <hip/hip_runtime.h>
#include <hip/hip_bf16.h>
#include <stdint.h>

// CrossAttention2d: n=16, c=1024, h=w=32 (hw=1024), S=256, c_enc=768, H=16, d=64.
// Pipeline: ln_stats -> norm+transpose(bf16) -> enc LN(bf16) -> cast weights ->
//   QT = ndT @ Wq^T + bq      (GEMM, Bt-form)
//   kv = enc_n @ Wkv^T + bkv  (GEMM, Bt-form)
//   attention per (n,head)    (MFMA bf16, softmax in regs)
//   out = x + Wo @ y + bo     (GEMM, Bt=yT, fp32 out + residual)

typedef __bf16 bf16x8 __attribute__((ext_vector_type(8)));
typedef float f32x4 __attribute__((ext_vector_type(4)));

__device__ __forceinline__ void gload_lds16(const void* g, void* l) {
  __builtin_amdgcn_global_load_lds(
      (const __attribute__((address_space(1))) void*)(uintptr_t)g,
      (__attribute__((address_space(3))) void*)(unsigned int)(uintptr_t)l,
      16, 0, 0);
}

// ---------- LN stats over channels: mu/rstd per (n,p) ----------
__global__ __launch_bounds__(256) void ln_stats_kernel(const float* __restrict__ x,
                                                       float* __restrict__ mu,
                                                       float* __restrict__ rstd) {
  int b = blockIdx.x;            // 256 blocks
  int n = b >> 4;
  int p0 = (b & 15) << 6;
  int pl = threadIdx.x & 63;
  int cg = threadIdx.x >> 6;     // 4 c-groups
  const float* xp = x + ((size_t)n << 20) + p0 + pl;
  float s = 0.f, s2 = 0.f;
  for (int c = cg; c < 1024; c += 4) {
    float v = xp[(size_t)c << 10];
    s += v; s2 += v * v;
  }
  __shared__ float ps[4][64], ps2[4][64];
  ps[cg][pl] = s; ps2[cg][pl] = s2;
  __syncthreads();
  if (threadIdx.x < 64) {
    float t  = ps[0][pl] + ps[1][pl] + ps[2][pl] + ps[3][pl];
    float t2 = ps2[0][pl] + ps2[1][pl] + ps2[2][pl] + ps2[3][pl];
    float m = t * (1.f / 1024.f);
    float var = t2 * (1.f / 1024.f) - m * m;
    int idx = (n << 10) + p0 + pl;
    mu[idx] = m;
    rstd[idx] = rsqrtf(var + 1e-5f);
  }
}

// ---------- normalize + transpose: ndT[n][p][c] bf16 ----------
__global__ __launch_bounds__(256) void norm_transpose_kernel(
    const float* __restrict__ x, const float* __restrict__ mu,
    const float* __restrict__ rstd, const float* __restrict__ gamma,
    const float* __restrict__ beta, __bf16* __restrict__ ndT) {
  int n = blockIdx.z;
  int p0 = blockIdx.x << 5;
  int c0 = blockIdx.y << 5;
  __shared__ float tile[32][33];
  int tc = threadIdx.x & 31;
  int tr = threadIdx.x >> 5;     // 0..7
  const float* xb = x + ((size_t)n << 20) + ((size_t)c0 << 10) + p0;
#pragma unroll
  for (int i = 0; i < 4; ++i) {
    int row = (i << 3) + tr;     // c_local
    tile[row][tc] = xb[((size_t)row << 10) + tc];
  }
  __syncthreads();
#pragma unroll
  for (int i = 0; i < 4; ++i) {
    int prow = (i << 3) + tr;    // p_local
    int cl = tc;                 // c_local
    int pidx = (n << 10) + p0 + prow;
    float v = (tile[cl][prow] - mu[pidx]) * rstd[pidx] * gamma[c0 + cl] + beta[c0 + cl];
    ndT[((size_t)((n << 10) + p0 + prow) << 10) + c0 + cl] = (__bf16)v;
  }
}

// ---------- enc LayerNorm (last dim 768) -> bf16 ----------
__global__ __launch_bounds__(256) void enc_ln_kernel(const float* __restrict__ enc,
    const float* __restrict__ gamma, const float* __restrict__ beta,
    __bf16* __restrict__ out) {
  int s = blockIdx.x, n = blockIdx.y;
  size_t base = ((size_t)n * 256 + s) * 768;
  int t = threadIdx.x;
  float v0 = enc[base + t], v1 = enc[base + t + 256], v2 = enc[base + t + 512];
  float sum = v0 + v1 + v2, sq = v0 * v0 + v1 * v1 + v2 * v2;
#pragma unroll
  for (int off = 32; off; off >>= 1) {
    sum += __shfl_down(sum, off);
    sq  += __shfl_down(sq, off);
  }
  __shared__ float red[8];
  int w = t >> 6;
  if ((t & 63) == 0) { red[w] = sum; red[4 + w] = sq; }
  __syncthreads();
  float tot  = red[0] + red[1] + red[2] + red[3];
  float tot2 = red[4] + red[5] + red[6] + red[7];
  float m = tot * (1.f / 768.f);
  float var = tot2 * (1.f / 768.f) - m * m;
  float rs = rsqrtf(var + 1e-5f);
  out[base + t]       = (__bf16)((v0 - m) * rs * gamma[t] + beta[t]);
  out[base + t + 256] = (__bf16)((v1 - m) * rs * gamma[t + 256] + beta[t + 256]);
  out[base + t + 512] = (__bf16)((v2 - m) * rs * gamma[t + 512] + beta[t + 512]);
}

// ---------- fp32 -> bf16 cast ----------
__global__ __launch_bounds__(256) void cast_bf16_kernel(const float* __restrict__ in,
                                                        __bf16* __restrict__ out, int count) {
  int stride = gridDim.x * 256;
  for (int i = blockIdx.x * 256 + threadIdx.x; i < count; i += stride)
    out[i] = (__bf16)in[i];
}

// ---------- GEMM: C[M][N] = A[M][K] * Bt[N][K]^T (+bias, +resid) ----------
// EPI 0: bias per N, bf16 out. EPI 1: bias per M + fp32 residual, fp32 out.
template <int EPI>
__global__ __launch_bounds__(256) void gemm_bt_kernel(
    const __bf16* __restrict__ A, const __bf16* __restrict__ Bt,
    const float* __restrict__ bias, const float* __restrict__ resid,
    void* __restrict__ Cout, int M, int N, int K,
    size_t sA, size_t sB, size_t sC, size_t sR) {
  int n0 = blockIdx.x << 7;
  int m0 = blockIdx.y << 7;
  int bz = blockIdx.z;
  const __bf16* Ab = A + sA * bz;
  const __bf16* Bb = Bt + sB * bz;

  int tid = threadIdx.x;
  int w = tid >> 6, lane = tid & 63;
  int l15 = lane & 15, hi = lane >> 4;
  int wr = w >> 1, wc = w & 1;

  __shared__ __align__(16) __bf16 lA[128 * 64];
  __shared__ __align__(16) __bf16 lB[128 * 64];

  f32x4 acc[4][4] = {};
  int xorkey = (l15 & 7) << 3;

  for (int kt = 0; kt < K; kt += 64) {
#pragma unroll
    for (int i = 0; i < 4; ++i) {
      int e = ((i << 8) + tid) << 3;   // (i*256+tid)*8 elements in 128x64 tile
      int r = e >> 6;
      int c = e & 63;
      int cs = c ^ ((r & 7) << 3);     // pre-swizzle source; LDS stays linear
      gload_lds16(Ab + (size_t)(m0 + r) * K + kt + cs, &lA[e]);
    }
#pragma unroll
    for (int i = 0; i < 4; ++i) {
      int e = ((i << 8) + tid) << 3;
      int r = e >> 6;
      int c = e & 63;
      int cs = c ^ ((r & 7) << 3);
      gload_lds16(Bb + (size_t)(n0 + r) * K + kt + cs, &lB[e]);
    }
    __syncthreads();
#pragma unroll
    for (int kk = 0; kk < 2; ++kk) {
      int ko = (kk << 5) + (hi << 3);
      bf16x8 af[4], bfr[4];
#pragma unroll
      for (int mi = 0; mi < 4; ++mi)
        af[mi] = *(const bf16x8*)&lA[(((wr << 6) + (mi << 4) + l15) << 6) + (ko ^ xorkey)];
#pragma unroll
      for (int ni = 0; ni < 4; ++ni)
        bfr[ni] = *(const bf16x8*)&lB[(((wc << 6) + (ni << 4) + l15) << 6) + (ko ^ xorkey)];
#pragma unroll
      for (int mi = 0; mi < 4; ++mi)
#pragma unroll
        for (int ni = 0; ni < 4; ++ni)
          acc[mi][ni] = __builtin_amdgcn_mfma_f32_16x16x32_bf16(af[mi], bfr[ni], acc[mi][ni], 0, 0, 0);
    }
    __syncthreads();
  }

#pragma unroll
  for (int mi = 0; mi < 4; ++mi) {
#pragma unroll
    for (int ni = 0; ni < 4; ++ni) {
      int col = n0 + (wc << 6) + (ni << 4) + l15;
      int rbase = m0 + (wr << 6) + (mi << 4) + (hi << 2);
      if (EPI == 0) {
        float bb = bias[col];
        __bf16* C = (__bf16*)Cout + sC * bz;
#pragma unroll
        for (int j = 0; j < 4; ++j)
          C[(size_t)(rbase + j) * N + col] = (__bf16)(acc[mi][ni][j] + bb);
      } else {
        float* C = (float*)Cout + sC * bz;
        const float* R = resid + sR * bz;
#pragma unroll
        for (int j = 0; j < 4; ++j) {
          int row = rbase + j;
          C[(size_t)row * N + col] = acc[mi][ni][j] + bias[row] + R[(size_t)row * N + col];
        }
      }
    }
  }
}

// ---------- attention: per (n, head, 64-query tile) ----------
__global__ __launch_bounds__(256) void attn_kernel(
    const __bf16* __restrict__ QT,   // [n][1024][1024]
    const __bf16* __restrict__ kv,   // [n][256][2048]
    const int* __restrict__ padding, // [n][256]
    __bf16* __restrict__ yT) {       // [n][1024][1024]
  int qb = blockIdx.x, h = blockIdx.y, n = blockIdx.z;
  int tid = threadIdx.x;
  int w = tid >> 6, lane = tid & 63;
  int l15 = lane & 15, hi = lane >> 4;

  __shared__ __align__(16) __bf16 lK[256 * 64];    // swizzled, linear LDS
  __shared__ __align__(16) __bf16 lVt[64 * 264];   // V^T, padded stride
  __shared__ __align__(16) __bf16 lP[64 * 264];    // P, padded stride
  __shared__ float lpad[256];

  const __bf16* kvb = kv + ((size_t)n << 19);
  // stage K via global_load_lds (source XOR-pre-swizzled)
#pragma unroll
  for (int i = 0; i < 8; ++i) {
    int e = ((i << 8) + tid) << 3;
    int s = e >> 6;
    int c = e & 63;
    int cs = c ^ ((s & 7) << 3);
    gload_lds16(kvb + ((size_t)s << 11) + (h << 6) + cs, &lK[e]);
  }
  // stage V^T (reg transpose)
  {
    int s = tid;
    const __bf16* vsrc = kvb + ((size_t)s << 11) + 1024 + (h << 6);
#pragma unroll
    for (int d0 = 0; d0 < 64; d0 += 8) {
      bf16x8 v8 = *(const bf16x8*)(vsrc + d0);
#pragma unroll
      for (int j = 0; j < 8; ++j) lVt[(d0 + j) * 264 + s] = v8[j];
    }
  }
  lpad[tid] = 10000.f * (float)padding[(n << 8) + tid];

  // Q fragments from global (A-operand layout)
  int q0w = (qb << 6) + (w << 4);
  const __bf16* qsrc = QT + ((size_t)((n << 10) + q0w + l15) << 10) + (h << 6) + (hi << 3);
  bf16x8 aq0 = *(const bf16x8*)qsrc;
  bf16x8 aq1 = *(const bf16x8*)(qsrc + 32);
  __syncthreads();

  // S = (Q K^T)/8 - 10000*pad
  f32x4 sa[16] = {};
  int xk = (l15 & 7) << 3;
#pragma unroll
  for (int ni = 0; ni < 16; ++ni) {
    int srow = (ni << 4) + l15;
    bf16x8 b0 = *(const bf16x8*)&lK[(srow << 6) + ((hi << 3) ^ xk)];
    bf16x8 b1 = *(const bf16x8*)&lK[(srow << 6) + ((32 + (hi << 3)) ^ xk)];
    sa[ni] = __builtin_amdgcn_mfma_f32_16x16x32_bf16(aq0, b0, sa[ni], 0, 0, 0);
    sa[ni] = __builtin_amdgcn_mfma_f32_16x16x32_bf16(aq1, b1, sa[ni], 0, 0, 0);
  }

  // softmax (row r = 4*hi+j; cols ni*16+l15); reduce across 16-lane group
  float dinv[4];
#pragma unroll
  for (int j = 0; j < 4; ++j) {
    float mx = -3.4e38f;
#pragma unroll
    for (int ni = 0; ni < 16; ++ni) {
      float v = sa[ni][j] * 0.125f - lpad[(ni << 4) + l15];
      sa[ni][j] = v;
      mx = fmaxf(mx, v);
    }
#pragma unroll
    for (int mm = 1; mm < 16; mm <<= 1) mx = fmaxf(mx, __shfl_xor(mx, mm));
    float sum = 0.f;
#pragma unroll
    for (int ni = 0; ni < 16; ++ni) {
      float p = __expf(sa[ni][j] - mx);
      sa[ni][j] = p;
      sum += p;
    }
#pragma unroll
    for (int mm = 1; mm < 16; mm <<= 1) sum += __shfl_xor(sum, mm);
    dinv[j] = 1.f / sum;
  }

  // P -> LDS (unnormalized bf16), rows owned by this wave
#pragma unroll
  for (int ni = 0; ni < 16; ++ni) {
    int scol = (ni << 4) + l15;
#pragma unroll
    for (int j = 0; j < 4; ++j)
      lP[((w << 4) + (hi << 2) + j) * 264 + scol] = (__bf16)sa[ni][j];
  }
  __syncthreads();

  // y = P V
  f32x4 ya[4] = {};
#pragma unroll
  for (int ks = 0; ks < 8; ++ks) {
    bf16x8 a = *(const bf16x8*)&lP[((w << 4) + l15) * 264 + (ks << 5) + (hi << 3)];
#pragma unroll
    for (int nd = 0; nd < 4; ++nd) {
      bf16x8 b = *(const bf16x8*)&lVt[((nd << 4) + l15) * 264 + (ks << 5) + (hi << 3)];
      ya[nd] = __builtin_amdgcn_mfma_f32_16x16x32_bf16(a, b, ya[nd], 0, 0, 0);
    }
  }

#pragma unroll
  for (int nd = 0; nd < 4; ++nd) {
    int d = (h << 6) + (nd << 4) + l15;
#pragma unroll
    for (int j = 0; j < 4; ++j) {
      int q = q0w + (hi << 2) + j;
      yT[((size_t)((n << 10) + q) << 10) + d] = (__bf16)(ya[nd][j] * dinv[j]);
    }
  }
}

extern "C" void kernel_launch(void* const* d_in, const int* in_sizes, int n_in,
                              void* d_out, int out_size, void* d_ws, size_t ws_size,
                              hipStream_t stream) {
  const float* x         = (const float*)d_in[0];
  const float* enc       = (const float*)d_in[1];
  const int*   padding   = (const int*)d_in[2];
  const float* gamma_dec = (const float*)d_in[3];
  const float* beta_dec  = (const float*)d_in[4];
  const float* gamma_enc = (const float*)d_in[5];
  const float* beta_enc  = (const float*)d_in[6];
  const float* Wq        = (const float*)d_in[7];
  const float* bq        = (const float*)d_in[8];
  const float* Wkv       = (const float*)d_in[9];
  const float* bkv       = (const float*)d_in[10];
  const float* Wo        = (const float*)d_in[11];
  const float* bo        = (const float*)d_in[12];
  float* out = (float*)d_out;

  char* ws = (char*)d_ws;
  // layout (bytes): ndT/yT alias 0..32M, QT 32M..64M, kv 64M..80M, encn 80M..86M,
  // WqB, WkvB, WoB, mu, rstd. total ~97.6 MB.
  __bf16* ndT  = (__bf16*)(ws);
  __bf16* yT   = (__bf16*)(ws);                 // reuse: ndT dead after Q-GEMM
  __bf16* QT   = (__bf16*)(ws + 33554432);
  __bf16* kvb  = (__bf16*)(ws + 67108864);
  __bf16* encn = (__bf16*)(ws + 83886080);
  __bf16* WqB  = (__bf16*)(ws + 90177536);
  __bf16* WkvB = (__bf16*)(ws + 92274688);
  __bf16* WoB  = (__bf16*)(ws + 95420416);
  float*  mu   = (float*)(ws + 97517568);
  float*  rstd = (float*)(ws + 97583104);

  ln_stats_kernel<<<256, 256, 0, stream>>>(x, mu, rstd);
  norm_transpose_kernel<<<dim3(32, 32, 16), 256, 0, stream>>>(x, mu, rstd, gamma_dec, beta_dec, ndT);
  enc_ln_kernel<<<dim3(256, 16), 256, 0, stream>>>(enc, gamma_enc, beta_enc, encn);
  cast_bf16_kernel<<<512, 256, 0, stream>>>(Wq, WqB, 1024 * 1024);
  cast_bf16_kernel<<<512, 256, 0, stream>>>(Wkv, WkvB, 2048 * 768);
  cast_bf16_kernel<<<512, 256, 0, stream>>>(Wo, WoB, 1024 * 1024);

  // QT[n][p][o] = ndT[n] @ Wq^T + bq
  gemm_bt_kernel<0><<<dim3(8, 8, 16), 256, 0, stream>>>(
      ndT, WqB, bq, nullptr, QT, 1024, 1024, 1024,
      (size_t)1024 * 1024, 0, (size_t)1024 * 1024, 0);
  // kv[n][s][j] = encn[n] @ Wkv^T + bkv
  gemm_bt_kernel<0><<<dim3(16, 2, 16), 256, 0, stream>>>(
      encn, WkvB, bkv, nullptr, kvb, 256, 2048, 768,
      (size_t)256 * 768, 0, (size_t)256 * 2048, 0);

  attn_kernel<<<dim3(16, 16, 16), 256, 0, stream>>>(QT, kvb, padding, yT);

  // out[n][o][p] = x + Wo @ y + bo   (Bt = yT[n][p][c])
  gemm_bt_kernel<1><<<dim3(8, 8, 16), 256, 0, stream>>>(
      WoB, yT, bo, x, out, 1024, 1024, 1024,
      0, (size_t)1024 * 1024, (size_t)1024 * 1024, (size_t)1024 * 1024);
}

// Round 2
// 274.010 us; speedup vs baseline: 1.2627x; 1.2627x over previous
//
#include <hip/hip_runtime.h>
#include <hip/hip_bf16.h>
#include <stdint.h>

// CrossAttention2d: n=16, c=1024, h=w=32 (hw=1024), S=256, c_enc=768, H=16, d=64.
// Pipeline: ln_stats -> norm+transpose(bf16) -> enc LN(bf16) -> cast weights ->
//   QT = ndT @ Wq^T + bq      (GEMM, Bt-form)
//   kv = enc_n @ Wkv^T + bkv  (GEMM, Bt-form)
//   attention per (n,head)    (MFMA bf16, softmax in regs)
//   out = x + Wo @ y + bo     (GEMM, Bt=yT, fp32 out + residual)

typedef __bf16 bf16x8 __attribute__((ext_vector_type(8)));
typedef float f32x4 __attribute__((ext_vector_type(4)));

__device__ __forceinline__ void gload_lds16(const void* g, void* l) {
  __builtin_amdgcn_global_load_lds(
      (const __attribute__((address_space(1))) void*)(uintptr_t)g,
      (__attribute__((address_space(3))) void*)(unsigned int)(uintptr_t)l,
      16, 0, 0);
}

// ---------- LN stats over channels: mu/rstd per (n,p) ----------
// grid 256 blocks (16 n x 16 p-chunks of 64 px), 1024 threads.
// Each thread: 16 float4 loads (4 px x its 16 c-values), LDS tree reduce.
__global__ __launch_bounds__(1024) void ln_stats_kernel(const float* __restrict__ x,
                                                        float* __restrict__ mu,
                                                        float* __restrict__ rstd) {
  int b = blockIdx.x;
  int n = b >> 4;
  int p0 = (b & 15) << 6;        // 64 pixels
  int t = threadIdx.x;
  int pl4 = t & 15;              // float4 index within the 64 px
  int cg = t >> 4;               // 0..63 c-group
  const f32x4* xp = (const f32x4*)(x + ((size_t)n << 20) + p0);
  f32x4 s = {0.f, 0.f, 0.f, 0.f}, s2 = {0.f, 0.f, 0.f, 0.f};
#pragma unroll
  for (int i = 0; i < 16; ++i) {
    int c = cg + (i << 6);
    f32x4 v = xp[(c << 8) + pl4];   // row stride 1024 floats = 256 float4
    s += v;
    s2 += v * v;
  }
  __shared__ f32x4 ls[64][16];
  __shared__ f32x4 ls2[64][16];
  ls[cg][pl4] = s;
  ls2[cg][pl4] = s2;
  __syncthreads();
  if (t < 64) {                  // 4 q-groups x 16 pl4: sum 16 rows each
    int q = t >> 4, p = t & 15;
    f32x4 a = {0.f, 0.f, 0.f, 0.f}, a2 = {0.f, 0.f, 0.f, 0.f};
#pragma unroll
    for (int i = 0; i < 16; ++i) {
      a += ls[(q << 4) + i][p];
      a2 += ls2[(q << 4) + i][p];
    }
    ls[q][p] = a;
    ls2[q][p] = a2;
  }
  __syncthreads();
  if (t < 16) {
    f32x4 tot = ls[0][t] + ls[1][t] + ls[2][t] + ls[3][t];
    f32x4 tot2 = ls2[0][t] + ls2[1][t] + ls2[2][t] + ls2[3][t];
    f32x4 m, r;
#pragma unroll
    for (int e = 0; e < 4; ++e) {
      float mm = tot[e] * (1.f / 1024.f);
      float var = tot2[e] * (1.f / 1024.f) - mm * mm;
      m[e] = mm;
      r[e] = rsqrtf(var + 1e-5f);
    }
    ((f32x4*)(mu + (n << 10) + p0))[t] = m;
    ((f32x4*)(rstd + (n << 10) + p0))[t] = r;
  }
}

// ---------- normalize + transpose: ndT[n][p][c] bf16 ----------
// 64x64 tile, float4 loads, bf16x8 stores, LDS stride 65 (conflict-free).
__global__ __launch_bounds__(256) void norm_transpose_kernel(
    const float* __restrict__ x, const float* __restrict__ mu,
    const float* __restrict__ rstd, const float* __restrict__ gamma,
    const float* __restrict__ beta, __bf16* __restrict__ ndT) {
  int n = blockIdx.z;
  int p0 = blockIdx.x << 6;
  int c0 = blockIdx.y << 6;
  __shared__ float tile[64][65];
  int t = threadIdx.x;
  int fc = t & 15;               // float4 col in p
  int rr = t >> 4;               // 0..15
  const float* xb = x + ((size_t)n << 20) + ((size_t)c0 << 10) + p0;
#pragma unroll
  for (int i = 0; i < 4; ++i) {
    int cl = (i << 4) + rr;
    f32x4 v = *(const f32x4*)(xb + ((size_t)cl << 10) + (fc << 2));
#pragma unroll
    for (int e = 0; e < 4; ++e) tile[cl][(fc << 2) + e] = v[e];
  }
  int cgp = t & 7;               // 8 c-groups of 8
  int pr = t >> 3;               // 0..31
  float g[8], bb[8];
#pragma unroll
  for (int k = 0; k < 8; ++k) {
    g[k] = gamma[c0 + (cgp << 3) + k];
    bb[k] = beta[c0 + (cgp << 3) + k];
  }
  __syncthreads();
#pragma unroll
  for (int it = 0; it < 2; ++it) {
    int pl = (it << 5) + pr;
    int gp = (n << 10) + p0 + pl;
    float m = mu[gp], r = rstd[gp];
    bf16x8 o;
#pragma unroll
    for (int k = 0; k < 8; ++k)
      o[k] = (__bf16)((tile[(cgp << 3) + k][pl] - m) * r * g[k] + bb[k]);
    *(bf16x8*)(ndT + ((size_t)gp << 10) + c0 + (cgp << 3)) = o;
  }
}

// ---------- enc LayerNorm (last dim 768) -> bf16 ----------
__global__ __launch_bounds__(256) void enc_ln_kernel(const float* __restrict__ enc,
    const float* __restrict__ gamma, const float* __restrict__ beta,
    __bf16* __restrict__ out) {
  int s = blockIdx.x, n = blockIdx.y;
  size_t base = ((size_t)n * 256 + s) * 768;
  int t = threadIdx.x;
  float v0 = enc[base + t], v1 = enc[base + t + 256], v2 = enc[base + t + 512];
  float sum = v0 + v1 + v2, sq = v0 * v0 + v1 * v1 + v2 * v2;
#pragma unroll
  for (int off = 32; off; off >>= 1) {
    sum += __shfl_down(sum, off);
    sq  += __shfl_down(sq, off);
  }
  __shared__ float red[8];
  int w = t >> 6;
  if ((t & 63) == 0) { red[w] = sum; red[4 + w] = sq; }
  __syncthreads();
  float tot  = red[0] + red[1] + red[2] + red[3];
  float tot2 = red[4] + red[5] + red[6] + red[7];
  float m = tot * (1.f / 768.f);
  float var = tot2 * (1.f / 768.f) - m * m;
  float rs = rsqrtf(var + 1e-5f);
  out[base + t]       = (__bf16)((v0 - m) * rs * gamma[t] + beta[t]);
  out[base + t + 256] = (__bf16)((v1 - m) * rs * gamma[t + 256] + beta[t + 256]);
  out[base + t + 512] = (__bf16)((v2 - m) * rs * gamma[t + 512] + beta[t + 512]);
}

// ---------- fp32 -> bf16 cast ----------
__global__ __launch_bounds__(256) void cast_bf16_kernel(const float* __restrict__ in,
                                                        __bf16* __restrict__ out, int count) {
  int stride = gridDim.x * 256;
  for (int i = blockIdx.x * 256 + threadIdx.x; i < count; i += stride)
    out[i] = (__bf16)in[i];
}

// ---------- GEMM: C[M][N] = A[M][K] * Bt[N][K]^T (+bias, +resid) ----------
// EPI 0: bias per N, bf16 out. EPI 1: bias per M + fp32 residual, fp32 out.
template <int EPI>
__global__ __launch_bounds__(256) void gemm_bt_kernel(
    const __bf16* __restrict__ A, const __bf16* __restrict__ Bt,
    const float* __restrict__ bias, const float* __restrict__ resid,
    void* __restrict__ Cout, int M, int N, int K,
    size_t sA, size_t sB, size_t sC, size_t sR) {
  int n0 = blockIdx.x << 7;
  int m0 = blockIdx.y << 7;
  int bz = blockIdx.z;
  const __bf16* Ab = A + sA * bz;
  const __bf16* Bb = Bt + sB * bz;

  int tid = threadIdx.x;
  int w = tid >> 6, lane = tid & 63;
  int l15 = lane & 15, hi = lane >> 4;
  int wr = w >> 1, wc = w & 1;

  __shared__ __align__(16) __bf16 lA[128 * 64];
  __shared__ __align__(16) __bf16 lB[128 * 64];

  f32x4 acc[4][4] = {};
  int xorkey = (l15 & 7) << 3;

  for (int kt = 0; kt < K; kt += 64) {
#pragma unroll
    for (int i = 0; i < 4; ++i) {
      int e = ((i << 8) + tid) << 3;   // (i*256+tid)*8 elements in 128x64 tile
      int r = e >> 6;
      int c = e & 63;
      int cs = c ^ ((r & 7) << 3);     // pre-swizzle source; LDS stays linear
      gload_lds16(Ab + (size_t)(m0 + r) * K + kt + cs, &lA[e]);
    }
#pragma unroll
    for (int i = 0; i < 4; ++i) {
      int e = ((i << 8) + tid) << 3;
      int r = e >> 6;
      int c = e & 63;
      int cs = c ^ ((r & 7) << 3);
      gload_lds16(Bb + (size_t)(n0 + r) * K + kt + cs, &lB[e]);
    }
    __syncthreads();
#pragma unroll
    for (int kk = 0; kk < 2; ++kk) {
      int ko = (kk << 5) + (hi << 3);
      bf16x8 af[4], bfr[4];
#pragma unroll
      for (int mi = 0; mi < 4; ++mi)
        af[mi] = *(const bf16x8*)&lA[(((wr << 6) + (mi << 4) + l15) << 6) + (ko ^ xorkey)];
#pragma unroll
      for (int ni = 0; ni < 4; ++ni)
        bfr[ni] = *(const bf16x8*)&lB[(((wc << 6) + (ni << 4) + l15) << 6) + (ko ^ xorkey)];
#pragma unroll
      for (int mi = 0; mi < 4; ++mi)
#pragma unroll
        for (int ni = 0; ni < 4; ++ni)
          acc[mi][ni] = __builtin_amdgcn_mfma_f32_16x16x32_bf16(af[mi], bfr[ni], acc[mi][ni], 0, 0, 0);
    }
    __syncthreads();
  }

#pragma unroll
  for (int mi = 0; mi < 4; ++mi) {
#pragma unroll
    for (int ni = 0; ni < 4; ++ni) {
      int col = n0 + (wc << 6) + (ni << 4) + l15;
      int rbase = m0 + (wr << 6) + (mi << 4) + (hi << 2);
      if (EPI == 0) {
        float bb = bias[col];
        __bf16* C = (__bf16*)Cout + sC * bz;
#pragma unroll
        for (int j = 0; j < 4; ++j)
          C[(size_t)(rbase + j) * N + col] = (__bf16)(acc[mi][ni][j] + bb);
      } else {
        float* C = (float*)Cout + sC * bz;
        const float* R = resid + sR * bz;
#pragma unroll
        for (int j = 0; j < 4; ++j) {
          int row = rbase + j;
          C[(size_t)row * N + col] = acc[mi][ni][j] + bias[row] + R[(size_t)row * N + col];
        }
      }
    }
  }
}

// ---------- attention: per (n, head, 64-query tile) ----------
__global__ __launch_bounds__(256) void attn_kernel(
    const __bf16* __restrict__ QT,   // [n][1024][1024]
    const __bf16* __restrict__ kv,   // [n][256][2048]
    const int* __restrict__ padding, // [n][256]
    __bf16* __restrict__ yT) {       // [n][1024][1024]
  int qb = blockIdx.x, h = blockIdx.y, n = blockIdx.z;
  int tid = threadIdx.x;
  int w = tid >> 6, lane = tid & 63;
  int l15 = lane & 15, hi = lane >> 4;

  __shared__ __align__(16) __bf16 lK[256 * 64];    // swizzled, linear LDS
  __shared__ __align__(16) __bf16 lVt[64 * 264];   // V^T, padded stride
  __shared__ __align__(16) __bf16 lP[64 * 264];    // P, padded stride
  __shared__ float lpad[256];

  const __bf16* kvb = kv + ((size_t)n << 19);
  // stage K via global_load_lds (source XOR-pre-swizzled)
#pragma unroll
  for (int i = 0; i < 8; ++i) {
    int e = ((i << 8) + tid) << 3;
    int s = e >> 6;
    int c = e & 63;
    int cs = c ^ ((s & 7) << 3);
    gload_lds16(kvb + ((size_t)s << 11) + (h << 6) + cs, &lK[e]);
  }
  // stage V^T (reg transpose)
  {
    int s = tid;
    const __bf16* vsrc = kvb + ((size_t)s << 11) + 1024 + (h << 6);
#pragma unroll
    for (int d0 = 0; d0 < 64; d0 += 8) {
      bf16x8 v8 = *(const bf16x8*)(vsrc + d0);
#pragma unroll
      for (int j = 0; j < 8; ++j) lVt[(d0 + j) * 264 + s] = v8[j];
    }
  }
  lpad[tid] = 10000.f * (float)padding[(n << 8) + tid];

  // Q fragments from global (A-operand layout)
  int q0w = (qb << 6) + (w << 4);
  const __bf16* qsrc = QT + ((size_t)((n << 10) + q0w + l15) << 10) + (h << 6) + (hi << 3);
  bf16x8 aq0 = *(const bf16x8*)qsrc;
  bf16x8 aq1 = *(const bf16x8*)(qsrc + 32);
  __syncthreads();

  // S = (Q K^T)/8 - 10000*pad
  f32x4 sa[16] = {};
  int xk = (l15 & 7) << 3;
#pragma unroll
  for (int ni = 0; ni < 16; ++ni) {
    int srow = (ni << 4) + l15;
    bf16x8 b0 = *(const bf16x8*)&lK[(srow << 6) + ((hi << 3) ^ xk)];
    bf16x8 b1 = *(const bf16x8*)&lK[(srow << 6) + ((32 + (hi << 3)) ^ xk)];
    sa[ni] = __builtin_amdgcn_mfma_f32_16x16x32_bf16(aq0, b0, sa[ni], 0, 0, 0);
    sa[ni] = __builtin_amdgcn_mfma_f32_16x16x32_bf16(aq1, b1, sa[ni], 0, 0, 0);
  }

  // softmax (row r = 4*hi+j; cols ni*16+l15); reduce across 16-lane group
  float dinv[4];
#pragma unroll
  for (int j = 0; j < 4; ++j) {
    float mx = -3.4e38f;
#pragma unroll
    for (int ni = 0; ni < 16; ++ni) {
      float v = sa[ni][j] * 0.125f - lpad[(ni << 4) + l15];
      sa[ni][j] = v;
      mx = fmaxf(mx, v);
    }
#pragma unroll
    for (int mm = 1; mm < 16; mm <<= 1) mx = fmaxf(mx, __shfl_xor(mx, mm));
    float sum = 0.f;
#pragma unroll
    for (int ni = 0; ni < 16; ++ni) {
      float p = __expf(sa[ni][j] - mx);
      sa[ni][j] = p;
      sum += p;
    }
#pragma unroll
    for (int mm = 1; mm < 16; mm <<= 1) sum += __shfl_xor(sum, mm);
    dinv[j] = 1.f / sum;
  }

  // P -> LDS (unnormalized bf16), rows owned by this wave
#pragma unroll
  for (int ni = 0; ni < 16; ++ni) {
    int scol = (ni << 4) + l15;
#pragma unroll
    for (int j = 0; j < 4; ++j)
      lP[((w << 4) + (hi << 2) + j) * 264 + scol] = (__bf16)sa[ni][j];
  }
  __syncthreads();

  // y = P V
  f32x4 ya[4] = {};
#pragma unroll
  for (int ks = 0; ks < 8; ++ks) {
    bf16x8 a = *(const bf16x8*)&lP[((w << 4) + l15) * 264 + (ks << 5) + (hi << 3)];
#pragma unroll
    for (int nd = 0; nd < 4; ++nd) {
      bf16x8 b = *(const bf16x8*)&lVt[((nd << 4) + l15) * 264 + (ks << 5) + (hi << 3)];
      ya[nd] = __builtin_amdgcn_mfma_f32_16x16x32_bf16(a, b, ya[nd], 0, 0, 0);
    }
  }

#pragma unroll
  for (int nd = 0; nd < 4; ++nd) {
    int d = (h << 6) + (nd << 4) + l15;
#pragma unroll
    for (int j = 0; j < 4; ++j) {
      int q = q0w + (hi << 2) + j;
      yT[((size_t)((n << 10) + q) << 10) + d] = (__bf16)(ya[nd][j] * dinv[j]);
    }
  }
}

extern "C" void kernel_launch(void* const* d_in, const int* in_sizes, int n_in,
                              void* d_out, int out_size, void* d_ws, size_t ws_size,
                              hipStream_t stream) {
  const float* x         = (const float*)d_in[0];
  const float* enc       = (const float*)d_in[1];
  const int*   padding   = (const int*)d_in[2];
  const float* gamma_dec = (const float*)d_in[3];
  const float* beta_dec  = (const float*)d_in[4];
  const float* gamma_enc = (const float*)d_in[5];
  const float* beta_enc  = (const float*)d_in[6];
  const float* Wq        = (const float*)d_in[7];
  const float* bq        = (const float*)d_in[8];
  const float* Wkv       = (const float*)d_in[9];
  const float* bkv       = (const float*)d_in[10];
  const float* Wo        = (const float*)d_in[11];
  const float* bo        = (const float*)d_in[12];
  float* out = (float*)d_out;

  char* ws = (char*)d_ws;
  // layout (bytes): ndT/yT alias 0..32M, QT 32M..64M, kv 64M..80M, encn 80M..86M,
  // WqB, WkvB, WoB, mu, rstd. total ~97.6 MB.
  __bf16* ndT  = (__bf16*)(ws);
  __bf16* yT   = (__bf16*)(ws);                 // reuse: ndT dead after Q-GEMM
  __bf16* QT   = (__bf16*)(ws + 33554432);
  __bf16* kvb  = (__bf16*)(ws + 67108864);
  __bf16* encn = (__bf16*)(ws + 83886080);
  __bf16* WqB  = (__bf16*)(ws + 90177536);
  __bf16* WkvB = (__bf16*)(ws + 92274688);
  __bf16* WoB  = (__bf16*)(ws + 95420416);
  float*  mu   = (float*)(ws + 97517568);
  float*  rstd = (float*)(ws + 97583104);

  ln_stats_kernel<<<256, 1024, 0, stream>>>(x, mu, rstd);
  norm_transpose_kernel<<<dim3(16, 16, 16), 256, 0, stream>>>(x, mu, rstd, gamma_dec, beta_dec, ndT);
  enc_ln_kernel<<<dim3(256, 16), 256, 0, stream>>>(enc, gamma_enc, beta_enc, encn);
  cast_bf16_kernel<<<512, 256, 0, stream>>>(Wq, WqB, 1024 * 1024);
  cast_bf16_kernel<<<512, 256, 0, stream>>>(Wkv, WkvB, 2048 * 768);
  cast_bf16_kernel<<<512, 256, 0, stream>>>(Wo, WoB, 1024 * 1024);

  // QT[n][p][o] = ndT[n] @ Wq^T + bq
  gemm_bt_kernel<0><<<dim3(8, 8, 16), 256, 0, stream>>>(
      ndT, WqB, bq, nullptr, QT, 1024, 1024, 1024,
      (size_t)1024 * 1024, 0, (size_t)1024 * 1024, 0);
  // kv[n][s][j] = encn[n] @ Wkv^T + bkv
  gemm_bt_kernel<0><<<dim3(16, 2, 16), 256, 0, stream>>>(
      encn, WkvB, bkv, nullptr, kvb, 256, 2048, 768,
      (size_t)256 * 768, 0, (size_t)256 * 2048, 0);

  attn_kernel<<<dim3(16, 16, 16), 256, 0, stream>>>(QT, kvb, padding, yT);

  // out[n][o][p] = x + Wo @ y + bo   (Bt = yT[n][p][c])
  gemm_bt_kernel<1><<<dim3(8, 8, 16), 256, 0, stream>>>(
      WoB, yT, bo, x, out, 1024, 1024, 1024,
      0, (size_t)1024 * 1024, (size_t)1024 * 1024, (size_t)1024 * 1024);
}